// Round 1
// baseline (1615.072 us; speedup 1.0000x reference)
//
#include <hip/hip_runtime.h>
#include <hip/hip_fp16.h>
#include <math.h>

// Problem constants: B=4, C=256, H=W=64 -> HW=4096
#define HW 4096
#define NC 256
#define NB 4
#define EPSF 1e-5f
#define TEN (NB * HW * NC)  // elements per output tensor = 4194304

typedef _Float16 half8 __attribute__((ext_vector_type(8)));
typedef _Float16 half4v __attribute__((ext_vector_type(4)));
typedef float f32x4 __attribute__((ext_vector_type(4)));

// ws layout (bytes):
//  [0, 16K)   stats f32: meanC[1024], rstdC[1024], meanS[1024], rstdS[1024]
//  QF : f16 [b][pix][256]  (pixel-major)
//  KF : f16 [b][pix][256]  (pixel-major)
//  VF : f16 [b][ch][4096]  (channel-major)
//  (V^2 hi/lo streams removed: computed in-register in attn_kernel)
#define STATS_BYTES (4096 * 4)
#define QF_OFF  (STATS_BYTES)
#define KF_OFF  (QF_OFF + TEN * 2)
#define VF_OFF  (KF_OFF + TEN * 2)

// async global->LDS, 16B per lane; LDS dest = wave-uniform base + lane*16
typedef const __attribute__((address_space(1))) void* gas_vp;
typedef __attribute__((address_space(3))) void* las_vp;
__device__ __forceinline__ void gload_lds16(const void* g, void* l) {
  __builtin_amdgcn_global_load_lds((gas_vp)g, (las_vp)l, 16, 0, 0);
}

// ---------------------------------------------------------------------------
// Kernel 1: per-(b,c) mean and rstd for content and style. (unchanged)
// ---------------------------------------------------------------------------
__global__ __launch_bounds__(256) void stats_kernel(
    const float* __restrict__ content, const float* __restrict__ style,
    float* __restrict__ ws) {
  int bc = blockIdx.x;
  const float* src = (bc < 1024 ? content : style) + (size_t)(bc & 1023) * HW;
  int t = threadIdx.x;
  const float4* s4 = (const float4*)src;
  float sum = 0.f, ss = 0.f;
#pragma unroll
  for (int n = 0; n < 4; ++n) {
    float4 v = s4[t + n * 256];
    sum += v.x + v.y + v.z + v.w;
    ss += v.x * v.x + v.y * v.y + v.z * v.z + v.w * v.w;
  }
#pragma unroll
  for (int m = 1; m < 64; m <<= 1) {
    sum += __shfl_xor(sum, m, 64);
    ss += __shfl_xor(ss, m, 64);
  }
  __shared__ float redS[4], redQ[4];
  int w = t >> 6;
  if ((t & 63) == 0) { redS[w] = sum; redQ[w] = ss; }
  __syncthreads();
  if (t == 0) {
    float S = redS[0] + redS[1] + redS[2] + redS[3];
    float Q2 = redQ[0] + redQ[1] + redQ[2] + redQ[3];
    float mean = S * (1.0f / HW);
    float var = (Q2 - S * mean) * (1.0f / (HW - 1));
    float rstd = rsqrtf(var + EPSF);
    float* meanArr = ws + (bc < 1024 ? 0 : 2048);
    float* rstdArr = meanArr + 1024;
    meanArr[bc & 1023] = mean;
    rstdArr[bc & 1023] = rstd;
  }
}

// ---------------------------------------------------------------------------
// Kernel 2: fused normalize + 1x1 conv; f16 outputs.
// (unchanged except: V^2 hi/lo streams no longer produced)
// ---------------------------------------------------------------------------
__global__ __launch_bounds__(256) void proj_kernel(
    const float* __restrict__ content, const float* __restrict__ style,
    const float* __restrict__ Wf, const float* __restrict__ bf,
    const float* __restrict__ Wg, const float* __restrict__ bg,
    const float* __restrict__ Wh, const float* __restrict__ bh,
    char* __restrict__ wsb) {
  float* ws = (float*)wsb;
  int pt = blockIdx.x;
  int ot = blockIdx.y;
  int z = blockIdx.z;
  int tensor = z >> 2, b = z & 3;

  const float* X; const float* Wm; const float* bias;
  const float* meanA = nullptr; const float* rstdA = nullptr;
  if (tensor == 0)      { X = content; Wm = Wf; bias = bf; meanA = ws;        rstdA = ws + 1024; }
  else if (tensor == 1) { X = style;   Wm = Wg; bias = bg; meanA = ws + 2048; rstdA = ws + 3072; }
  else                  { X = style;   Wm = Wh; bias = bh; }

  __shared__ float Xs[32 * 132];
  __shared__ float Wt[32 * 68];

  int t = threadIdx.x;
  int p0 = pt * 128, o0 = ot * 64;
  int o_base = (t >> 4) * 4;
  int p_base = (t & 15) * 8;

  float bb[4];
  { float4 b4 = *(const float4*)&bias[o0 + o_base];
    bb[0] = b4.x; bb[1] = b4.y; bb[2] = b4.z; bb[3] = b4.w; }
  float acc[4][8];
#pragma unroll
  for (int oo = 0; oo < 4; ++oo)
#pragma unroll
    for (int pp = 0; pp < 8; ++pp) acc[oo][pp] = bb[oo];

  const float4* X4 = (const float4*)X;
  const float4* Wm4 = (const float4*)Wm;

  for (int kc = 0; kc < 8; ++kc) {
    int k0 = kc * 32;
    __syncthreads();
#pragma unroll
    for (int n = 0; n < 4; ++n) {
      int f = t + n * 256;
      int kk = f >> 5, p4 = f & 31;
      float4 v = X4[(size_t)(b * NC + k0 + kk) * (HW / 4) + (p0 / 4) + p4];
      if (tensor < 2) {
        float mC = meanA[b * NC + k0 + kk], rC = rstdA[b * NC + k0 + kk];
        v.x = (v.x - mC) * rC; v.y = (v.y - mC) * rC;
        v.z = (v.z - mC) * rC; v.w = (v.w - mC) * rC;
      }
      *(float4*)&Xs[kk * 132 + p4 * 4] = v;
    }
#pragma unroll
    for (int n = 0; n < 2; ++n) {
      int f = t + n * 256;
      int o = f >> 3, k4 = f & 7;
      float4 v = Wm4[(size_t)(o0 + o) * (NC / 4) + kc * 8 + k4];
      Wt[(k4 * 4 + 0) * 68 + o] = v.x;
      Wt[(k4 * 4 + 1) * 68 + o] = v.y;
      Wt[(k4 * 4 + 2) * 68 + o] = v.z;
      Wt[(k4 * 4 + 3) * 68 + o] = v.w;
    }
    __syncthreads();
#pragma unroll
    for (int kk = 0; kk < 32; ++kk) {
      float4 w4 = *(float4*)&Wt[kk * 68 + o_base];
      float4 xa = *(float4*)&Xs[kk * 132 + p_base];
      float4 xb = *(float4*)&Xs[kk * 132 + p_base + 4];
      float wv[4] = {w4.x, w4.y, w4.z, w4.w};
      float xv[8] = {xa.x, xa.y, xa.z, xa.w, xb.x, xb.y, xb.z, xb.w};
#pragma unroll
      for (int oo = 0; oo < 4; ++oo)
#pragma unroll
        for (int pp = 0; pp < 8; ++pp)
          acc[oo][pp] = fmaf(wv[oo], xv[pp], acc[oo][pp]);
    }
  }

  if (tensor < 2) {
    _Float16* dst = (_Float16*)(wsb + (tensor == 0 ? QF_OFF : KF_OFF));
#pragma unroll
    for (int pp = 0; pp < 8; ++pp) {
      half4v h;
      h[0] = (_Float16)acc[0][pp]; h[1] = (_Float16)acc[1][pp];
      h[2] = (_Float16)acc[2][pp]; h[3] = (_Float16)acc[3][pp];
      *(half4v*)&dst[((size_t)(b * HW) + p0 + p_base + pp) * 256 + o0 + o_base] = h;
    }
  } else {
    _Float16* dV = (_Float16*)(wsb + VF_OFF);
#pragma unroll
    for (int oo = 0; oo < 4; ++oo) {
      int ch = o0 + o_base + oo;
      half8 hv;
#pragma unroll
      for (int pp = 0; pp < 8; ++pp) hv[pp] = (_Float16)acc[oo][pp];
      size_t base = ((size_t)(b * NC) + ch) * HW + p0 + p_base;
      *(half8*)&dV[base] = hv;
    }
  }
}

// ---------------------------------------------------------------------------
// Kernel 3: flash attention, mfma_f32_16x16x32_f16.
// RESTRUCTURED for occupancy: block = 256 thr = 4 waves, q-tile 32,
// grid = 512 blocks -> 4 blocks/CU co-resident (was 256 blocks = 1/CU, 23% occ).
// Wave = (qh 0..1, chh 0..1): 16 queries x 128 channels per wave.
// LDS 32KB single-buffered: K[16K] | V[16K]; P (2KB) aliases K.
// Staging via global_load_lds with PRE-SWIZZLED global source addresses
// (linear LDS dest, unchanged swizzled reads) -> zero staging VGPRs.
// V^2 hi/lo computed in-register from the V fragment (packed f16 mul/fma,
// bit-identical to the previous precomputed split).
// XCD swizzle: batch = (bid&7)>>1 so each XCD's 4MB L2 holds its batch's K+V.
// ---------------------------------------------------------------------------
__global__ __launch_bounds__(256, 4) void attn_kernel(
    const char* __restrict__ wsb, const float* __restrict__ content,
    float* __restrict__ dout) {
  const _Float16* Qf = (const _Float16*)(wsb + QF_OFF);
  const _Float16* Kf = (const _Float16*)(wsb + KF_OFF);
  const _Float16* Vf = (const _Float16*)(wsb + VF_OFF);
  const float* meanC = (const float*)wsb;
  const float* rstdC = meanC + 1024;

  int bid = blockIdx.x;
  int xcd = bid & 7;
  int b = xcd >> 1;                          // 2 XCDs per batch
  int qt = ((bid >> 3) << 1) | (xcd & 1);    // 0..127, bijective
  int q0 = qt * 32;

  int t = threadIdx.x;
  int lane = t & 63;
  int w = t >> 6;      // 0..3
  int qh = w >> 1;     // 0..1: which 16 queries
  int chh = w & 1;     // 0..1: which 128 channels
  int ml = lane & 15;
  int kg4 = lane >> 4;

  __shared__ int4 smem[2048];                 // 32 KB
  _Float16* Kt = (_Float16*)smem;             // 16 KB (int4 idx 0..1023)
  _Float16* Vt = (_Float16*)(smem + 1024);    // 16 KB
  _Float16* Pt = (_Float16*)smem;             // 2 KB, aliases Kt

  // ---- Q A-frags: 16 queries x 256 ch per wave (32 VGPRs) ----
  half8 Aq[8];
#pragma unroll
  for (int ks = 0; ks < 8; ++ks) {
    size_t off = ((size_t)(b * HW) + q0 + qh * 16 + ml) * 256 + ks * 32 + kg4 * 8;
    Aq[ks] = *(const half8*)(Qf + off);
  }

  f32x4 accm[8], accs[8];
#pragma unroll
  for (int nt = 0; nt < 8; ++nt) {
    accm[nt] = (f32x4){0.f, 0.f, 0.f, 0.f};
    accs[nt] = (f32x4){0.f, 0.f, 0.f, 0.f};
  }
  float mrun[4], lrun[4];
#pragma unroll
  for (int r = 0; r < 4; ++r) { mrun[r] = -INFINITY; lrun[r] = 0.f; }

  const int4* Kg = (const int4*)(Kf + (size_t)b * HW * 256);  // [key][32 granules]
  const int4* Vg = (const int4*)(Vf + (size_t)b * NC * HW);   // [ch][512 granules]

  // Pre-swizzled per-lane source indices. LDS layout (read side, unchanged):
  //  K: int4 idx = c*32 + (key ^ c)   (c = ch-granule 0..31, key 0..31)
  //  V: int4 idx = kg*256 + (ch ^ kg) (kg = key-granule 0..3, ch 0..255)
  // Wave w writes chunks n = w*4+j (64 int4 each, lane-linear dest):
  //  K chunk: c = n*2 + (lane>>5), pos = lane&31 -> src key = pos^c
  //  V chunk: kg = w, chpos = j*64+lane        -> src ch  = chpos^w
  int ksrc[4], vsrc[4];
  {
    int l5 = lane >> 5;
    int l31 = lane & 31;
#pragma unroll
    for (int j = 0; j < 4; ++j) {
      int c = (w * 4 + j) * 2 + l5;
      ksrc[j] = (l31 ^ c) * 32 + c;                  // + kt*1024
      vsrc[j] = ((j * 64 + lane) ^ w) * 512 + w;     // + kt*4
    }
  }

  for (int kt = 0; kt < 128; ++kt) {
    __syncthreads();  // A: prev tile's LDS reads (QK on Kt, PV on Vt/Pt) done
#pragma unroll
    for (int j = 0; j < 4; ++j) {
      gload_lds16(Kg + (size_t)(kt * 1024 + ksrc[j]), smem + (w * 4 + j) * 64);
      gload_lds16(Vg + (size_t)(vsrc[j] + kt * 4),    smem + 1024 + (w * 4 + j) * 64);
    }
    __syncthreads();  // B: tiles visible (syncthreads drains vmcnt)

    // ---- QK^T ----
    f32x4 S[2];
    S[0] = (f32x4){0.f, 0.f, 0.f, 0.f};
    S[1] = (f32x4){0.f, 0.f, 0.f, 0.f};
#pragma unroll
    for (int ks = 0; ks < 8; ++ks) {
      int c = ks * 4 + kg4;
#pragma unroll
      for (int nt = 0; nt < 2; ++nt) {
        int key = nt * 16 + ml;
        half8 Bk = *(const half8*)(Kt + (c * 32 + (key ^ c)) * 8);
        S[nt] = __builtin_amdgcn_mfma_f32_16x16x32_f16(Aq[ks], Bk, S[nt], 0, 0, 0);
      }
    }

    // ---- online softmax ----
    bool noup = true;
    float alpha[4];
#pragma unroll
    for (int r = 0; r < 4; ++r) {
      float tm = fmaxf(S[0][r], S[1][r]);
      tm = fmaxf(tm, __shfl_xor(tm, 1, 64));
      tm = fmaxf(tm, __shfl_xor(tm, 2, 64));
      tm = fmaxf(tm, __shfl_xor(tm, 4, 64));
      tm = fmaxf(tm, __shfl_xor(tm, 8, 64));
      float mold = mrun[r];
      float mn = fmaxf(mold, tm);
      float a = __expf(mold - mn);
      alpha[r] = a;
      noup = noup && (mn == mold);
      mrun[r] = mn;
      float rs = 0.f;
#pragma unroll
      for (int nt = 0; nt < 2; ++nt) {
        float p = __expf(S[nt][r] - mn);
        _Float16 ph = (_Float16)p;
        S[nt][r] = (float)ph;  // keep rounded value
        rs += (float)ph;
      }
      rs += __shfl_xor(rs, 1, 64);
      rs += __shfl_xor(rs, 2, 64);
      rs += __shfl_xor(rs, 4, 64);
      rs += __shfl_xor(rs, 8, 64);
      lrun[r] = lrun[r] * a + rs;
    }
    if (!__all((int)noup)) {
#pragma unroll
      for (int nt = 0; nt < 8; ++nt)
#pragma unroll
        for (int r = 0; r < 4; ++r) {
          accm[nt][r] *= alpha[r];
          accs[nt][r] *= alpha[r];
        }
    }

    __syncthreads();  // C: all QK reads of Kt done before P overwrites it

    // ---- P -> LDS in A-layout: Pt[(keygran*32 + qloc)*8 + key&7] ----
    if (chh == 0) {
#pragma unroll
      for (int nt = 0; nt < 2; ++nt)
#pragma unroll
        for (int r = 0; r < 4; ++r) {
          int qloc = qh * 16 + kg4 * 4 + r;
          int key = nt * 16 + ml;
          Pt[((key >> 3) * 32 + qloc) * 8 + (key & 7)] = (_Float16)S[nt][r];
        }
    }
    __syncthreads();  // D: P visible

    // ---- PV: V^2 hi/lo computed in-register (exact split, packed f16) ----
    half8 Ap = *(const half8*)(Pt + (kg4 * 32 + qh * 16 + ml) * 8);
#pragma unroll
    for (int nt = 0; nt < 8; ++nt) {
      int ch = chh * 128 + nt * 16 + ml;
      int gi = (kg4 * 256 + (ch ^ kg4)) * 8;
      union { half8 v; __half2 h2[4]; } bv, bh, bl;
      bv.v = *(const half8*)(Vt + gi);
#pragma unroll
      for (int u = 0; u < 4; ++u) {
        __half2 hh = __hmul2(bv.h2[u], bv.h2[u]);               // RN(v^2)
        bh.h2[u] = hh;
        bl.h2[u] = __hfma2(bv.h2[u], bv.h2[u], __hneg2(hh));    // exact residual
      }
      accm[nt] = __builtin_amdgcn_mfma_f32_16x16x32_f16(Ap, bv.v, accm[nt], 0, 0, 0);
      accs[nt] = __builtin_amdgcn_mfma_f32_16x16x32_f16(Ap, bh.v, accs[nt], 0, 0, 0);
      accs[nt] = __builtin_amdgcn_mfma_f32_16x16x32_f16(Ap, bl.v, accs[nt], 0, 0, 0);
    }
  }

  // ---- finalize ----
  float inv[4];
#pragma unroll
  for (int r = 0; r < 4; ++r) inv[r] = 1.0f / lrun[r];
#pragma unroll
  for (int nt = 0; nt < 8; ++nt)
#pragma unroll
    for (int r = 0; r < 4; ++r) {
      float mu = accm[nt][r] * inv[r];
      float s2 = accs[nt][r] * inv[r];
      float var = s2 - mu * mu;
      accm[nt][r] = mu;
      accs[nt][r] = sqrtf(fmaxf(var, 0.f));
    }

  // ---- coalesced epilogue via LDS transpose: 4 phases of 64 channels ----
  float* MUL = (float*)smem;            // [64][36]
  float* SDL = MUL + 64 * 36;           // total 18 KB <= 32 KB
#pragma unroll 1
  for (int ph = 0; ph < 4; ++ph) {
    __syncthreads();
    if (chh == (ph >> 1)) {
      int ntb = (ph & 1) * 4;
#pragma unroll
      for (int nn = 0; nn < 4; ++nn)
#pragma unroll
        for (int r = 0; r < 4; ++r) {
          int row64 = nn * 16 + ml;
          int ql = qh * 16 + kg4 * 4 + r;
          MUL[row64 * 36 + ql] = accm[ntb + nn][r];
          SDL[row64 * 36 + ql] = accs[ntb + nn][r];
        }
    }
    __syncthreads();
    int qq = (t & 7) * 4;
    int chl0 = t >> 3;
#pragma unroll
    for (int i = 0; i < 2; ++i) {
      int chl = chl0 + 32 * i;
      int ch = ph * 64 + chl;
      float4 mu4 = *(float4*)&MUL[chl * 36 + qq];
      float4 sd4 = *(float4*)&SDL[chl * 36 + qq];
      size_t base = ((size_t)(b * NC) + ch) * HW + q0 + qq;
      float4 c4 = *(const float4*)&content[base];
      float mC = meanC[b * NC + ch];
      float rC = rstdC[b * NC + ch];
      float4 o4;
      o4.x = sd4.x * ((c4.x - mC) * rC) + mu4.x;
      o4.y = sd4.y * ((c4.y - mC) * rC) + mu4.y;
      o4.z = sd4.z * ((c4.z - mC) * rC) + mu4.z;
      o4.w = sd4.w * ((c4.w - mC) * rC) + mu4.w;
      *(float4*)&dout[base] = o4;
      *(float4*)&dout[TEN + base] = mu4;
      *(float4*)&dout[2 * TEN + base] = sd4;
    }
  }
}

// ---------------------------------------------------------------------------
extern "C" void kernel_launch(void* const* d_in, const int* in_sizes, int n_in,
                              void* d_out, int out_size, void* d_ws, size_t ws_size,
                              hipStream_t stream) {
  const float* content = (const float*)d_in[0];
  const float* style   = (const float*)d_in[1];
  const float* Wf = (const float*)d_in[2];
  const float* bf = (const float*)d_in[3];
  const float* Wg = (const float*)d_in[4];
  const float* bg = (const float*)d_in[5];
  const float* Wh = (const float*)d_in[6];
  const float* bh = (const float*)d_in[7];
  char* wsb = (char*)d_ws;
  float* out = (float*)d_out;

  hipLaunchKernelGGL(stats_kernel, dim3(2048), dim3(256), 0, stream,
                     content, style, (float*)wsb);
  hipLaunchKernelGGL(proj_kernel, dim3(32, 4, 12), dim3(256), 0, stream,
                     content, style, Wf, bf, Wg, bg, Wh, bh, wsb);
  hipLaunchKernelGGL(attn_kernel, dim3(512), dim3(256), 0, stream,
                     wsb, content, out);
}

// Round 2
// 822.659 us; speedup vs baseline: 1.9632x; 1.9632x over previous
//
#include <hip/hip_runtime.h>
#include <hip/hip_fp16.h>
#include <math.h>

// Problem constants: B=4, C=256, H=W=64 -> HW=4096
#define HW 4096
#define NC 256
#define NB 4
#define EPSF 1e-5f
#define TEN (NB * HW * NC)  // elements per output tensor = 4194304

typedef _Float16 half8 __attribute__((ext_vector_type(8)));
typedef _Float16 half4v __attribute__((ext_vector_type(4)));
typedef float f32x4 __attribute__((ext_vector_type(4)));

// ws layout (bytes):
//  [0, 16K)   stats f32: meanC[1024], rstdC[1024], meanS[1024], rstdS[1024]
//  QF : f16 [b][pix][256]  (pixel-major)
//  KF : f16 [b][pix][256]  (pixel-major)
//  VF : f16 [b][ch][4096]  (channel-major)
//  TICKET: 256 ints (one per (b,qt64) pair), zeroed by stats_kernel
//  ML: per pair 64q x {m,l} f32 from the losing half-block
#define STATS_BYTES (4096 * 4)
#define QF_OFF  (STATS_BYTES)
#define KF_OFF  (QF_OFF + TEN * 2)
#define VF_OFF  (KF_OFF + TEN * 2)
#define TICKET_OFF (VF_OFF + TEN * 2)
#define ML_OFF (TICKET_OFF + 1024)

// ---------------------------------------------------------------------------
// Kernel 1: per-(b,c) mean and rstd for content and style; zero tickets.
// ---------------------------------------------------------------------------
__global__ __launch_bounds__(256) void stats_kernel(
    const float* __restrict__ content, const float* __restrict__ style,
    float* __restrict__ ws) {
  int bc = blockIdx.x;
  int t = threadIdx.x;
  if (bc == 0 && t < 256) ((int*)((char*)ws + TICKET_OFF))[t] = 0;
  const float* src = (bc < 1024 ? content : style) + (size_t)(bc & 1023) * HW;
  const float4* s4 = (const float4*)src;
  float sum = 0.f, ss = 0.f;
#pragma unroll
  for (int n = 0; n < 4; ++n) {
    float4 v = s4[t + n * 256];
    sum += v.x + v.y + v.z + v.w;
    ss += v.x * v.x + v.y * v.y + v.z * v.z + v.w * v.w;
  }
#pragma unroll
  for (int m = 1; m < 64; m <<= 1) {
    sum += __shfl_xor(sum, m, 64);
    ss += __shfl_xor(ss, m, 64);
  }
  __shared__ float redS[4], redQ[4];
  int w = t >> 6;
  if ((t & 63) == 0) { redS[w] = sum; redQ[w] = ss; }
  __syncthreads();
  if (t == 0) {
    float S = redS[0] + redS[1] + redS[2] + redS[3];
    float Q2 = redQ[0] + redQ[1] + redQ[2] + redQ[3];
    float mean = S * (1.0f / HW);
    float var = (Q2 - S * mean) * (1.0f / (HW - 1));
    float rstd = rsqrtf(var + EPSF);
    float* meanArr = ws + (bc < 1024 ? 0 : 2048);
    float* rstdArr = meanArr + 1024;
    meanArr[bc & 1023] = mean;
    rstdArr[bc & 1023] = rstd;
  }
}

// ---------------------------------------------------------------------------
// Kernel 2: fused normalize + 1x1 conv; f16 outputs (V only; V^2 in attn).
// ---------------------------------------------------------------------------
__global__ __launch_bounds__(256) void proj_kernel(
    const float* __restrict__ content, const float* __restrict__ style,
    const float* __restrict__ Wf, const float* __restrict__ bf,
    const float* __restrict__ Wg, const float* __restrict__ bg,
    const float* __restrict__ Wh, const float* __restrict__ bh,
    char* __restrict__ wsb) {
  float* ws = (float*)wsb;
  int pt = blockIdx.x;
  int ot = blockIdx.y;
  int z = blockIdx.z;
  int tensor = z >> 2, b = z & 3;

  const float* X; const float* Wm; const float* bias;
  const float* meanA = nullptr; const float* rstdA = nullptr;
  if (tensor == 0)      { X = content; Wm = Wf; bias = bf; meanA = ws;        rstdA = ws + 1024; }
  else if (tensor == 1) { X = style;   Wm = Wg; bias = bg; meanA = ws + 2048; rstdA = ws + 3072; }
  else                  { X = style;   Wm = Wh; bias = bh; }

  __shared__ float Xs[32 * 132];
  __shared__ float Wt[32 * 68];

  int t = threadIdx.x;
  int p0 = pt * 128, o0 = ot * 64;
  int o_base = (t >> 4) * 4;
  int p_base = (t & 15) * 8;

  float bb[4];
  { float4 b4 = *(const float4*)&bias[o0 + o_base];
    bb[0] = b4.x; bb[1] = b4.y; bb[2] = b4.z; bb[3] = b4.w; }
  float acc[4][8];
#pragma unroll
  for (int oo = 0; oo < 4; ++oo)
#pragma unroll
    for (int pp = 0; pp < 8; ++pp) acc[oo][pp] = bb[oo];

  const float4* X4 = (const float4*)X;
  const float4* Wm4 = (const float4*)Wm;

  for (int kc = 0; kc < 8; ++kc) {
    int k0 = kc * 32;
    __syncthreads();
#pragma unroll
    for (int n = 0; n < 4; ++n) {
      int f = t + n * 256;
      int kk = f >> 5, p4 = f & 31;
      float4 v = X4[(size_t)(b * NC + k0 + kk) * (HW / 4) + (p0 / 4) + p4];
      if (tensor < 2) {
        float mC = meanA[b * NC + k0 + kk], rC = rstdA[b * NC + k0 + kk];
        v.x = (v.x - mC) * rC; v.y = (v.y - mC) * rC;
        v.z = (v.z - mC) * rC; v.w = (v.w - mC) * rC;
      }
      *(float4*)&Xs[kk * 132 + p4 * 4] = v;
    }
#pragma unroll
    for (int n = 0; n < 2; ++n) {
      int f = t + n * 256;
      int o = f >> 3, k4 = f & 7;
      float4 v = Wm4[(size_t)(o0 + o) * (NC / 4) + kc * 8 + k4];
      Wt[(k4 * 4 + 0) * 68 + o] = v.x;
      Wt[(k4 * 4 + 1) * 68 + o] = v.y;
      Wt[(k4 * 4 + 2) * 68 + o] = v.z;
      Wt[(k4 * 4 + 3) * 68 + o] = v.w;
    }
    __syncthreads();
#pragma unroll
    for (int kk = 0; kk < 32; ++kk) {
      float4 w4 = *(float4*)&Wt[kk * 68 + o_base];
      float4 xa = *(float4*)&Xs[kk * 132 + p_base];
      float4 xb = *(float4*)&Xs[kk * 132 + p_base + 4];
      float wv[4] = {w4.x, w4.y, w4.z, w4.w};
      float xv[8] = {xa.x, xa.y, xa.z, xa.w, xb.x, xb.y, xb.z, xb.w};
#pragma unroll
      for (int oo = 0; oo < 4; ++oo)
#pragma unroll
        for (int pp = 0; pp < 8; ++pp)
          acc[oo][pp] = fmaf(wv[oo], xv[pp], acc[oo][pp]);
    }
  }

  if (tensor < 2) {
    _Float16* dst = (_Float16*)(wsb + (tensor == 0 ? QF_OFF : KF_OFF));
#pragma unroll
    for (int pp = 0; pp < 8; ++pp) {
      half4v h;
      h[0] = (_Float16)acc[0][pp]; h[1] = (_Float16)acc[1][pp];
      h[2] = (_Float16)acc[2][pp]; h[3] = (_Float16)acc[3][pp];
      *(half4v*)&dst[((size_t)(b * HW) + p0 + p_base + pp) * 256 + o0 + o_base] = h;
    }
  } else {
    _Float16* dV = (_Float16*)(wsb + VF_OFF);
#pragma unroll
    for (int oo = 0; oo < 4; ++oo) {
      int ch = o0 + o_base + oo;
      half8 hv;
#pragma unroll
      for (int pp = 0; pp < 8; ++pp) hv[pp] = (_Float16)acc[oo][pp];
      size_t base = ((size_t)(b * NC) + ch) * HW + p0 + p_base;
      *(half8*)&dV[base] = hv;
    }
  }
}

// ---------------------------------------------------------------------------
// Kernel 3: flash attention, split-K = 2. Proven 711us structure:
// block = 512 thr = 8 waves; q-tile 64; wave = (qh 0..3, chh 0..1) =
// 16 queries x 128 channels (accm/accs 64 VGPR, Aq 32, ~112 total, no spill
// at __launch_bounds__(512,2)). Each block does 64 of 128 k-tiles ->
// grid 512 blocks, 4096 waves = 16 waves/CU (LDS 64KB -> 2 blocks/CU).
// V^2 hi/lo in-register from the V fragment (exact split, bit-identical).
// Partial merge: ticket protocol. Loser writes raw Spv/Spv2 to dout
// mean/std slots + (m,l) to ws, release-ticket; winner (partner provably
// resident+past k-loop when ticket==1) spins on ticket==3, merges with
// exact softmax rescale, writes all 3 outputs.
// XCD swizzle: group g = bid&7 -> (b,kh) pinned to one XCD (2MB K/V half
// fits its 4MB L2); partner pair on XCD g^4, adjacent dispatch.
// ---------------------------------------------------------------------------
__global__ __launch_bounds__(512, 2) void attn_kernel(
    char* __restrict__ wsb, const float* __restrict__ content,
    float* __restrict__ dout) {
  const _Float16* Qf = (const _Float16*)(wsb + QF_OFF);
  const _Float16* Kf = (const _Float16*)(wsb + KF_OFF);
  const _Float16* Vf = (const _Float16*)(wsb + VF_OFF);
  const float* meanC = (const float*)wsb;
  const float* rstdC = meanC + 1024;
  int* tickets = (int*)(wsb + TICKET_OFF);

  int raw = blockIdx.x;      // 0..511
  int g = raw & 7;           // XCD group
  int b = g & 3;
  int kh = g >> 2;           // k-half 0/1
  int qt = raw >> 3;         // 0..63
  int q0 = qt * 64;
  int pair = b * 64 + qt;

  int t = threadIdx.x;
  int lane = t & 63;
  int w = t >> 6;     // 0..7
  int qh = w >> 1;    // 0..3: which 16 queries
  int chh = w & 1;    // 0..1: which 128 channels
  int ml = lane & 15;
  int kg4 = lane >> 4;

  __shared__ int4 smem[4096];  // 64 KB
  _Float16* Kt = (_Float16*)smem;                     // 16 KB
  _Float16* Vt = (_Float16*)((char*)smem + 16384);    // 16 KB
  _Float16* Pt = (_Float16*)smem;                     // 4 KB, aliases Kt
  int4* kt16 = (int4*)Kt;
  int4* v16  = (int4*)Vt;

  // ---- Q A-frags: 16 queries x 256 ch per wave (32 VGPRs) ----
  half8 Aq[8];
#pragma unroll
  for (int ks = 0; ks < 8; ++ks) {
    size_t off = ((size_t)(b * HW) + q0 + qh * 16 + ml) * 256 + ks * 32 + kg4 * 8;
    Aq[ks] = *(const half8*)(Qf + off);
  }

  f32x4 accm[8], accs[8];
#pragma unroll
  for (int nt = 0; nt < 8; ++nt) {
    accm[nt] = (f32x4){0.f, 0.f, 0.f, 0.f};
    accs[nt] = (f32x4){0.f, 0.f, 0.f, 0.f};
  }
  float mrun[4], lrun[4];
#pragma unroll
  for (int r = 0; r < 4; ++r) { mrun[r] = -INFINITY; lrun[r] = 0.f; }

  // ---- staging geometry (reg-prefetch double buffer, K + V streams) ----
  int k_key = t >> 4;   // 0..31
  int k_c0  = t & 15;   // granules c0, c0+16
  const int4* Kg = (const int4*)(Kf + (size_t)b * HW * 256);
  int v_kg  = t & 3;
  int v_chb = t >> 2;   // 0..127; ch = v_chb + 128*i
  const int4* Vg = (const int4*)(Vf + (size_t)b * NC * HW);

  int gt0 = kh * 64;
  int4 pk[2], pv[2];
#pragma unroll
  for (int i = 0; i < 2; ++i) {
    int c = k_c0 + 16 * i;
    pk[i] = Kg[(size_t)(gt0 * 32 + k_key) * 32 + c];
    int ch = v_chb + 128 * i;
    pv[i] = Vg[(size_t)ch * (HW / 8) + gt0 * 4 + v_kg];
  }

  for (int ktl = 0; ktl < 64; ++ktl) {
    __syncthreads();  // prev iter's LDS reads done

    // ---- write staged regs to LDS (swizzled) ----
#pragma unroll
    for (int i = 0; i < 2; ++i) {
      int c = k_c0 + 16 * i;
      kt16[c * 32 + (k_key ^ c)] = pk[i];
      int ch = v_chb + 128 * i;
      v16[v_kg * 256 + (ch ^ v_kg)] = pv[i];
    }
    // ---- prefetch next tile within this half (wraps; overlaps compute) ----
    {
      int gtn = kh * 64 + ((ktl + 1) & 63);
#pragma unroll
      for (int i = 0; i < 2; ++i) {
        int c = k_c0 + 16 * i;
        pk[i] = Kg[(size_t)(gtn * 32 + k_key) * 32 + c];
        int ch = v_chb + 128 * i;
        pv[i] = Vg[(size_t)ch * (HW / 8) + gtn * 4 + v_kg];
      }
    }
    __syncthreads();  // tiles visible

    // ---- QK^T ----
    f32x4 S[2];
    S[0] = (f32x4){0.f, 0.f, 0.f, 0.f};
    S[1] = (f32x4){0.f, 0.f, 0.f, 0.f};
#pragma unroll
    for (int ks = 0; ks < 8; ++ks) {
#pragma unroll
      for (int nt = 0; nt < 2; ++nt) {
        int key = nt * 16 + ml;
        int c = ks * 4 + kg4;
        half8 Bk = *(const half8*)(Kt + (c * 32 + (key ^ c)) * 8);
        S[nt] = __builtin_amdgcn_mfma_f32_16x16x32_f16(Aq[ks], Bk, S[nt], 0, 0, 0);
      }
    }

    // ---- online softmax ----
    bool noup = true;
    float alpha[4];
#pragma unroll
    for (int r = 0; r < 4; ++r) {
      float tm = fmaxf(S[0][r], S[1][r]);
      tm = fmaxf(tm, __shfl_xor(tm, 1, 64));
      tm = fmaxf(tm, __shfl_xor(tm, 2, 64));
      tm = fmaxf(tm, __shfl_xor(tm, 4, 64));
      tm = fmaxf(tm, __shfl_xor(tm, 8, 64));
      float mold = mrun[r];
      float mn = fmaxf(mold, tm);
      float a = __expf(mold - mn);
      alpha[r] = a;
      noup = noup && (mn == mold);
      mrun[r] = mn;
      float rs = 0.f;
#pragma unroll
      for (int nt = 0; nt < 2; ++nt) {
        float p = __expf(S[nt][r] - mn);
        _Float16 ph = (_Float16)p;
        S[nt][r] = (float)ph;  // keep rounded value
        rs += (float)ph;
      }
      rs += __shfl_xor(rs, 1, 64);
      rs += __shfl_xor(rs, 2, 64);
      rs += __shfl_xor(rs, 4, 64);
      rs += __shfl_xor(rs, 8, 64);
      lrun[r] = lrun[r] * a + rs;
    }
    if (!__all((int)noup)) {
#pragma unroll
      for (int nt = 0; nt < 8; ++nt)
#pragma unroll
        for (int r = 0; r < 4; ++r) {
          accm[nt][r] *= alpha[r];
          accs[nt][r] *= alpha[r];
        }
    }

    __syncthreads();  // all QK reads of Kt done before P overwrites it

    // ---- P -> LDS in A-layout: Pt[(keygran*64 + qloc)*8 + key&7] ----
    if (chh == 0) {
#pragma unroll
      for (int nt = 0; nt < 2; ++nt)
#pragma unroll
        for (int r = 0; r < 4; ++r) {
          int qloc = qh * 16 + kg4 * 4 + r;
          int key = nt * 16 + ml;
          Pt[((key >> 3) * 64 + qloc) * 8 + (key & 7)] = (_Float16)S[nt][r];
        }
    }
    __syncthreads();  // P visible

    // ---- PV: V^2 hi/lo in-register (exact split, packed f16) ----
    half8 Ap = *(const half8*)(Pt + (kg4 * 64 + qh * 16 + ml) * 8);
#pragma unroll
    for (int nt = 0; nt < 8; ++nt) {
      int ch = chh * 128 + nt * 16 + ml;
      int gi = (kg4 * 256 + (ch ^ kg4)) * 8;
      union { half8 v; __half2 h2[4]; } bv, bh, bl;
      bv.v = *(const half8*)(Vt + gi);
#pragma unroll
      for (int u = 0; u < 4; ++u) {
        __half2 hh = __hmul2(bv.h2[u], bv.h2[u]);             // RN(v^2)
        bh.h2[u] = hh;
        bl.h2[u] = __hfma2(bv.h2[u], bv.h2[u], __hneg2(hh));  // exact residual
      }
      accm[nt] = __builtin_amdgcn_mfma_f32_16x16x32_f16(Ap, bv.v, accm[nt], 0, 0, 0);
      accs[nt] = __builtin_amdgcn_mfma_f32_16x16x32_f16(Ap, bh.v, accs[nt], 0, 0, 0);
      accs[nt] = __builtin_amdgcn_mfma_f32_16x16x32_f16(Ap, bl.v, accs[nt], 0, 0, 0);
    }
  }

  // ==== merge of the two k-halves (ticket protocol; raw sums kept) ====
  __syncthreads();  // k-loop LDS reads done before smem reuse
  int* tickp = tickets + pair;
  int* tl = (int*)((char*)smem + 61440);
  if (t == 0) *tl = __hip_atomic_fetch_add(tickp, 1, __ATOMIC_ACQ_REL, __HIP_MEMORY_SCOPE_AGENT);
  __syncthreads();
  int ret = *tl;

  float* MUL = (float*)smem;            // [64][68] raw Spv
  float* SDL = MUL + 64 * 68;           // [64][68] raw Spv2  (34.8 KB total)
  float* MLg = (float*)(wsb + ML_OFF) + pair * 128;

  if (ret == 0) {
    // ---- loser: publish raw partials ----
    if (chh == 0 && ml == 0) {
#pragma unroll
      for (int r = 0; r < 4; ++r) {
        int q = qh * 16 + kg4 * 4 + r;
        MLg[q * 2] = mrun[r];
        MLg[q * 2 + 1] = lrun[r];
      }
    }
#pragma unroll 1
    for (int ph = 0; ph < 4; ++ph) {
      __syncthreads();
      if (chh == (ph >> 1)) {
        int ntb = (ph & 1) * 4;
#pragma unroll
        for (int nn = 0; nn < 4; ++nn)
#pragma unroll
          for (int r = 0; r < 4; ++r) {
            int row64 = nn * 16 + ml;
            int ql = qh * 16 + kg4 * 4 + r;
            MUL[row64 * 68 + ql] = accm[ntb + nn][r];
            SDL[row64 * 68 + ql] = accs[ntb + nn][r];
          }
      }
      __syncthreads();
      int qq = (t & 15) * 4;
#pragma unroll
      for (int i = 0; i < 2; ++i) {
        int chl = (t >> 4) + 32 * i;
        int ch = ph * 64 + chl;
        float4 mu4 = *(float4*)&MUL[chl * 68 + qq];
        float4 sd4 = *(float4*)&SDL[chl * 68 + qq];
        size_t base = ((size_t)(b * NC) + ch) * HW + q0 + qq;
        *(float4*)&dout[TEN + base] = mu4;
        *(float4*)&dout[2 * TEN + base] = sd4;
      }
    }
    __threadfence();
    __syncthreads();
    if (t == 0) __hip_atomic_fetch_add(tickp, 1, __ATOMIC_RELEASE, __HIP_MEMORY_SCOPE_AGENT);
  } else {
    // ---- winner: wait for partner data (partner provably running) ----
    if (t == 0) {
      while (__hip_atomic_load(tickp, __ATOMIC_ACQUIRE, __HIP_MEMORY_SCOPE_AGENT) < 3)
        __builtin_amdgcn_s_sleep(8);
    }
    __syncthreads();
    __threadfence();  // acquire for all threads before reading partner data

    // per-q merge coefficients into LDS (regions above MUL/SDL's 34.8 KB)
    float* cAL = (float*)((char*)smem + 59904);   // 64 f32
    float* cBL = cAL + 64;                        // 64 f32
    float* mlB = (float*)((char*)smem + 60544);   // 128 f32 own m,l
    if (chh == 0 && ml == 0) {
#pragma unroll
      for (int r = 0; r < 4; ++r) {
        int q = qh * 16 + kg4 * 4 + r;
        mlB[q * 2] = mrun[r];
        mlB[q * 2 + 1] = lrun[r];
      }
    }
    __syncthreads();
    if (t < 64) {
      float mA = MLg[t * 2], lA = MLg[t * 2 + 1];
      float mB = mlB[t * 2], lB = mlB[t * 2 + 1];
      float m = fmaxf(mA, mB);
      float eA = __expf(mA - m), eB = __expf(mB - m);
      float il = 1.0f / (eA * lA + eB * lB);
      cAL[t] = eA * il;
      cBL[t] = eB * il;
    }
    __syncthreads();

#pragma unroll 1
    for (int ph = 0; ph < 4; ++ph) {
      __syncthreads();
      if (chh == (ph >> 1)) {
        int ntb = (ph & 1) * 4;
#pragma unroll
        for (int nn = 0; nn < 4; ++nn)
#pragma unroll
          for (int r = 0; r < 4; ++r) {
            int row64 = nn * 16 + ml;
            int ql = qh * 16 + kg4 * 4 + r;
            MUL[row64 * 68 + ql] = accm[ntb + nn][r];
            SDL[row64 * 68 + ql] = accs[ntb + nn][r];
          }
      }
      __syncthreads();
      int qq = (t & 15) * 4;
      float4 cA4 = *(float4*)&cAL[qq];
      float4 cB4 = *(float4*)&cBL[qq];
#pragma unroll
      for (int i = 0; i < 2; ++i) {
        int chl = (t >> 4) + 32 * i;
        int ch = ph * 64 + chl;
        float4 m4 = *(float4*)&MUL[chl * 68 + qq];
        float4 s4 = *(float4*)&SDL[chl * 68 + qq];
        size_t base = ((size_t)(b * NC) + ch) * HW + q0 + qq;
        float4 pm4 = *(const float4*)&dout[TEN + base];
        float4 ps4 = *(const float4*)&dout[2 * TEN + base];
        float4 mu4, sd4;
        mu4.x = cB4.x * m4.x + cA4.x * pm4.x;
        mu4.y = cB4.y * m4.y + cA4.y * pm4.y;
        mu4.z = cB4.z * m4.z + cA4.z * pm4.z;
        mu4.w = cB4.w * m4.w + cA4.w * pm4.w;
        float s2x = cB4.x * s4.x + cA4.x * ps4.x;
        float s2y = cB4.y * s4.y + cA4.y * ps4.y;
        float s2z = cB4.z * s4.z + cA4.z * ps4.z;
        float s2w = cB4.w * s4.w + cA4.w * ps4.w;
        sd4.x = sqrtf(fmaxf(s2x - mu4.x * mu4.x, 0.f));
        sd4.y = sqrtf(fmaxf(s2y - mu4.y * mu4.y, 0.f));
        sd4.z = sqrtf(fmaxf(s2z - mu4.z * mu4.z, 0.f));
        sd4.w = sqrtf(fmaxf(s2w - mu4.w * mu4.w, 0.f));
        float4 c4 = *(const float4*)&content[base];
        float mC = meanC[b * NC + ch];
        float rC = rstdC[b * NC + ch];
        float4 o4;
        o4.x = sd4.x * ((c4.x - mC) * rC) + mu4.x;
        o4.y = sd4.y * ((c4.y - mC) * rC) + mu4.y;
        o4.z = sd4.z * ((c4.z - mC) * rC) + mu4.z;
        o4.w = sd4.w * ((c4.w - mC) * rC) + mu4.w;
        *(float4*)&dout[base] = o4;
        *(float4*)&dout[TEN + base] = mu4;
        *(float4*)&dout[2 * TEN + base] = sd4;
      }
    }
  }
}

// ---------------------------------------------------------------------------
extern "C" void kernel_launch(void* const* d_in, const int* in_sizes, int n_in,
                              void* d_out, int out_size, void* d_ws, size_t ws_size,
                              hipStream_t stream) {
  const float* content = (const float*)d_in[0];
  const float* style   = (const float*)d_in[1];
  const float* Wf = (const float*)d_in[2];
  const float* bf = (const float*)d_in[3];
  const float* Wg = (const float*)d_in[4];
  const float* bg = (const float*)d_in[5];
  const float* Wh = (const float*)d_in[6];
  const float* bh = (const float*)d_in[7];
  char* wsb = (char*)d_ws;
  float* out = (float*)d_out;

  hipLaunchKernelGGL(stats_kernel, dim3(2048), dim3(256), 0, stream,
                     content, style, (float*)wsb);
  hipLaunchKernelGGL(proj_kernel, dim3(32, 4, 12), dim3(256), 0, stream,
                     content, style, Wf, bf, Wg, bg, Wh, bh, wsb);
  hipLaunchKernelGGL(attn_kernel, dim3(512), dim3(512), 0, stream,
                     wsb, content, out);
}